// Round 7
// baseline (37.689 us; speedup 1.0000x reference)
//
#include <hip/hip_runtime.h>

// Problem constants (from reference)
#define N_ATOMS   500000
#define N_ALT     4
#define NB        2      // N_BATCH
#define NC        4      // N_CHAIN
#define NR        50000  // N_RES
#define SG_HASH   16
#define TEMP      298.0f

// Output layout (flat float32):
//   [0, 1600000)            residueEnergy (2,4,50000,4)
//   [1600000, 3600000)      atomEnergy    (500000,4)
//   [3600000, 3600000+P)    sulfur        (P,) as 0.0/1.0
#define RESE_SIZE  (NB * NC * NR * N_ALT)   // 1,600,000
#define ATOME_SIZE (N_ATOMS * N_ALT)        // 2,000,000
#define ZERO_F4    ((RESE_SIZE + ATOME_SIZE) / 4)   // 900,000 float4 stores

#define MASK_W64   ((N_ATOMS + 63) / 64)    // 7813 u64 = 62,504 B
#define MASK_W32   (MASK_W64 * 2)           // 15626 u32
#define MASK_V4    ((MASK_W32 + 3) / 4)     // 3907 uint4 (pad to 15628 words)

#define PPT 16                               // pairs per thread (single pass)

// ---------------------------------------------------------------------------
// Kernel A (prep): zero resE+atomE with float4 stores AND build the packed
// SG bitmask via __ballot — one launch.
// ---------------------------------------------------------------------------
__global__ __launch_bounds__(1024) void prep_kernel(
    const int* __restrict__ adesc,              // (N,4)
    float* __restrict__ zero_base,              // resE (zero 3.6M floats)
    unsigned long long* __restrict__ mask)      // (MASK_W64,)
{
    int i = blockIdx.x * 1024 + threadIdx.x;

    if (i < ZERO_F4)
        reinterpret_cast<float4*>(zero_base)[i] = make_float4(0.f, 0.f, 0.f, 0.f);

    bool s = false;
    if (i < N_ATOMS) s = (adesc[(size_t)i * 4 + 3] == SG_HASH);
    unsigned long long b = __ballot(s);
    if (i < N_ATOMS && (threadIdx.x & 63) == 0) mask[i >> 6] = b;
}

// ---------------------------------------------------------------------------
// Cold path: full energy + scatter for a sulfur pair (~0.1% of pairs).
// ---------------------------------------------------------------------------
__device__ __forceinline__ void heavy_pair(
    int p0, int p1,
    const float* __restrict__ coords,
    const int*   __restrict__ adesc,
    const int*   __restrict__ altmask,
    float* __restrict__ resE,
    float* __restrict__ atomE)
{
    int4 d0 = *reinterpret_cast<const int4*>(adesc + (size_t)p0 * 4);
    int4 d1 = *reinterpret_cast<const int4*>(adesc + (size_t)p1 * 4);

    float dx = coords[(size_t)p0 * 3 + 0] - coords[(size_t)p1 * 3 + 0] + 1e-6f;
    float dy = coords[(size_t)p0 * 3 + 1] - coords[(size_t)p1 * 3 + 1] + 1e-6f;
    float dz = coords[(size_t)p0 * 3 + 2] - coords[(size_t)p1 * 3 + 2] + 1e-6f;
    float dist = sqrtf(dx * dx + dy * dy + dz * dz);

    float rd = fabsf((float)(d0.z - d1.z));      // sulfur => rd >= 1, log safe
    float energy = -0.001f * TEMP * (2.1f + 2.9823825f * logf(rd))
                 + 5.0f * fabsf(dist - 2.04f);
    float netE = 0.5f * energy;

    int4 m0 = *reinterpret_cast<const int4*>(altmask + (size_t)p0 * 4);
    int4 m1 = *reinterpret_cast<const int4*>(altmask + (size_t)p1 * 4);

    int f0 = ((d0.x * NC + d0.y) * NR + d0.z) * N_ALT;
    int f1 = ((d1.x * NC + d1.y) * NR + d1.z) * N_ALT;

    const int* m0p = &m0.x;
    const int* m1p = &m1.x;
#pragma unroll
    for (int a = 0; a < N_ALT; ++a) {
        if (m0p[a] & m1p[a]) {
            atomicAdd(atomE + (size_t)p0 * N_ALT + a, netE);
            atomicAdd(atomE + (size_t)p1 * N_ALT + a, netE);
            atomicAdd(resE + f0 + a, netE);
            atomicAdd(resE + f1 + a, netE);
        }
    }
}

__device__ __forceinline__ bool probe2(const unsigned int* __restrict__ lm,
                                       int a, int b) {
    unsigned m = (lm[a >> 5] >> (a & 31)) & (lm[b >> 5] >> (b & 31));
    return m & 1u;
}

// ---------------------------------------------------------------------------
// Kernel B (single pass, 16 pairs/thread):
//   1. issue all 8 int4 pair loads (128 B/thread in flight)
//   2. broadcast the 62.5 KB SG bitmask into LDS (uint4) — hides load latency
//   3. __syncthreads, 32 LDS probes, 4x float4 sulfur stores
//   4. rare heavy path (inline, exec-masked)
// 1024-thread blocks, 62.5 KB LDS -> 2 blocks/CU.
// ---------------------------------------------------------------------------
__global__ __launch_bounds__(1024) void disulfide_pair_kernel(
    const float* __restrict__ coords,
    const int*   __restrict__ adesc,    // (N,4)
    const int*   __restrict__ pairs,    // (P,2)
    const int*   __restrict__ altmask,  // (N,4) 0/1
    const unsigned int* __restrict__ sgmask32,
    float* __restrict__ resE,
    float* __restrict__ atomE,
    float* __restrict__ sulfur,
    int P)
{
    __shared__ unsigned int lmask[MASK_V4 * 4];   // 62,512 B (8 B pad)

    const int tid = blockIdx.x * 1024 + threadIdx.x;
    const int i0  = tid * PPT;
    const bool active = (i0 < P);   // P % PPT == 0, so full batch in-bounds

    // --- phase 1: issue the pair-stream loads early -----------------------
    int4 v0, v1, v2, v3, v4, v5, v6, v7;
    if (active) {
        const int4* pp = reinterpret_cast<const int4*>(pairs + (size_t)i0 * 2);
        v0 = pp[0]; v1 = pp[1]; v2 = pp[2]; v3 = pp[3];
        v4 = pp[4]; v5 = pp[5]; v6 = pp[6]; v7 = pp[7];
    }

    // --- phase 2: broadcast bitmask into LDS (overlaps load latency) ------
    {
        const uint4* g4 = reinterpret_cast<const uint4*>(sgmask32);
        uint4* l4 = reinterpret_cast<uint4*>(lmask);
#pragma unroll
        for (int k = 0; k < 4; ++k) {
            int w = threadIdx.x + k * 1024;
            if (w < MASK_V4) l4[w] = g4[w];
        }
    }
    __syncthreads();

    if (!active) return;

    // --- phase 3: probes + sulfur stores -----------------------------------
    bool s[PPT];
    s[0]  = probe2(lmask, v0.x, v0.y);  s[1]  = probe2(lmask, v0.z, v0.w);
    s[2]  = probe2(lmask, v1.x, v1.y);  s[3]  = probe2(lmask, v1.z, v1.w);
    s[4]  = probe2(lmask, v2.x, v2.y);  s[5]  = probe2(lmask, v2.z, v2.w);
    s[6]  = probe2(lmask, v3.x, v3.y);  s[7]  = probe2(lmask, v3.z, v3.w);
    s[8]  = probe2(lmask, v4.x, v4.y);  s[9]  = probe2(lmask, v4.z, v4.w);
    s[10] = probe2(lmask, v5.x, v5.y);  s[11] = probe2(lmask, v5.z, v5.w);
    s[12] = probe2(lmask, v6.x, v6.y);  s[13] = probe2(lmask, v6.z, v6.w);
    s[14] = probe2(lmask, v7.x, v7.y);  s[15] = probe2(lmask, v7.z, v7.w);

    float4* sp = reinterpret_cast<float4*>(sulfur + i0);
#pragma unroll
    for (int q = 0; q < 4; ++q) {
        sp[q] = make_float4(s[q*4+0] ? 1.0f : 0.0f, s[q*4+1] ? 1.0f : 0.0f,
                            s[q*4+2] ? 1.0f : 0.0f, s[q*4+3] ? 1.0f : 0.0f);
    }

    // --- phase 4: rare heavy path ------------------------------------------
    if (s[0])  heavy_pair(v0.x, v0.y, coords, adesc, altmask, resE, atomE);
    if (s[1])  heavy_pair(v0.z, v0.w, coords, adesc, altmask, resE, atomE);
    if (s[2])  heavy_pair(v1.x, v1.y, coords, adesc, altmask, resE, atomE);
    if (s[3])  heavy_pair(v1.z, v1.w, coords, adesc, altmask, resE, atomE);
    if (s[4])  heavy_pair(v2.x, v2.y, coords, adesc, altmask, resE, atomE);
    if (s[5])  heavy_pair(v2.z, v2.w, coords, adesc, altmask, resE, atomE);
    if (s[6])  heavy_pair(v3.x, v3.y, coords, adesc, altmask, resE, atomE);
    if (s[7])  heavy_pair(v3.z, v3.w, coords, adesc, altmask, resE, atomE);
    if (s[8])  heavy_pair(v4.x, v4.y, coords, adesc, altmask, resE, atomE);
    if (s[9])  heavy_pair(v4.z, v4.w, coords, adesc, altmask, resE, atomE);
    if (s[10]) heavy_pair(v5.x, v5.y, coords, adesc, altmask, resE, atomE);
    if (s[11]) heavy_pair(v5.z, v5.w, coords, adesc, altmask, resE, atomE);
    if (s[12]) heavy_pair(v6.x, v6.y, coords, adesc, altmask, resE, atomE);
    if (s[13]) heavy_pair(v6.z, v6.w, coords, adesc, altmask, resE, atomE);
    if (s[14]) heavy_pair(v7.x, v7.y, coords, adesc, altmask, resE, atomE);
    if (s[15]) heavy_pair(v7.z, v7.w, coords, adesc, altmask, resE, atomE);
}

extern "C" void kernel_launch(void* const* d_in, const int* in_sizes, int n_in,
                              void* d_out, int out_size, void* d_ws, size_t ws_size,
                              hipStream_t stream) {
    const float* coords  = (const float*)d_in[0];
    const int*   adesc   = (const int*)d_in[1];
    // d_in[2] = atom_number (unused)
    const int*   pairs   = (const int*)d_in[3];
    const int*   altmask = (const int*)d_in[4];
    // d_in[5] = partners (unused), d_in[6] = facc (unused)

    const int P = in_sizes[3] / 2;   // 8,000,000

    float* out    = (float*)d_out;
    float* resE   = out;
    float* atomE  = out + RESE_SIZE;
    float* sulfur = out + RESE_SIZE + ATOME_SIZE;

    unsigned long long* sgmask = (unsigned long long*)d_ws;   // 62.5 KB

    // Kernel A: zero accumulated outputs + build SG bitmask (one launch).
    {
        const int threads = 1024;
        const int blocks  = (ZERO_F4 + threads - 1) / threads;   // 879
        prep_kernel<<<blocks, threads, 0, stream>>>(adesc, resE, sgmask);
    }

    // Kernel B: single-pass pair streaming with LDS-resident bitmask.
    {
        const int threads = 1024;
        const int work    = (P + PPT - 1) / PPT;                 // 500,000
        const int blocks  = (work + threads - 1) / threads;      // 489
        disulfide_pair_kernel<<<blocks, threads, 0, stream>>>(
            coords, adesc, pairs, altmask, (const unsigned int*)sgmask,
            resE, atomE, sulfur, P);
    }
}

// Round 8
// 30.274 us; speedup vs baseline: 1.2449x; 1.2449x over previous
//
#include <hip/hip_runtime.h>

// Problem constants (from reference)
#define N_ATOMS   500000
#define N_ALT     4
#define NB        2      // N_BATCH
#define NC        4      // N_CHAIN
#define NR        50000  // N_RES
#define SG_HASH   16
#define TEMP      298.0f

// Output layout (flat float32):
//   [0, 1600000)            residueEnergy (2,4,50000,4)
//   [1600000, 3600000)      atomEnergy    (500000,4)
//   [3600000, 3600000+P)    sulfur        (P,) as 0.0/1.0
#define RESE_SIZE  (NB * NC * NR * N_ALT)   // 1,600,000
#define ATOME_SIZE (N_ATOMS * N_ALT)        // 2,000,000
#define ZERO_F4    ((RESE_SIZE + ATOME_SIZE) / 4)   // 900,000 float4 stores

#define MASK_W64   ((N_ATOMS + 63) / 64)    // 7813 u64 = 62,504 B
#define MASK_W32   (MASK_W64 * 2)           // 15626 u32
#define MASK_V4    ((MASK_W32 + 3) / 4)     // 3907 uint4

// ---------------------------------------------------------------------------
// Kernel A (prep): zero resE+atomE with float4 stores AND build the packed
// SG bitmask via __ballot — one launch.
// ---------------------------------------------------------------------------
__global__ __launch_bounds__(1024) void prep_kernel(
    const int* __restrict__ adesc,              // (N,4)
    float* __restrict__ zero_base,              // resE (zero 3.6M floats)
    unsigned long long* __restrict__ mask)      // (MASK_W64,)
{
    int i = blockIdx.x * 1024 + threadIdx.x;

    if (i < ZERO_F4)
        reinterpret_cast<float4*>(zero_base)[i] = make_float4(0.f, 0.f, 0.f, 0.f);

    bool s = false;
    if (i < N_ATOMS) s = (adesc[(size_t)i * 4 + 3] == SG_HASH);
    unsigned long long b = __ballot(s);
    if (i < N_ATOMS && (threadIdx.x & 63) == 0) mask[i >> 6] = b;
}

// ---------------------------------------------------------------------------
// Cold path: full energy + scatter for a sulfur pair (~0.1% of pairs).
// ---------------------------------------------------------------------------
__device__ __forceinline__ void heavy_pair(
    int p0, int p1,
    const float* __restrict__ coords,
    const int*   __restrict__ adesc,
    const int*   __restrict__ altmask,
    float* __restrict__ resE,
    float* __restrict__ atomE)
{
    int4 d0 = *reinterpret_cast<const int4*>(adesc + (size_t)p0 * 4);
    int4 d1 = *reinterpret_cast<const int4*>(adesc + (size_t)p1 * 4);

    float dx = coords[(size_t)p0 * 3 + 0] - coords[(size_t)p1 * 3 + 0] + 1e-6f;
    float dy = coords[(size_t)p0 * 3 + 1] - coords[(size_t)p1 * 3 + 1] + 1e-6f;
    float dz = coords[(size_t)p0 * 3 + 2] - coords[(size_t)p1 * 3 + 2] + 1e-6f;
    float dist = sqrtf(dx * dx + dy * dy + dz * dz);

    float rd = fabsf((float)(d0.z - d1.z));      // sulfur => rd >= 1, log safe
    float energy = -0.001f * TEMP * (2.1f + 2.9823825f * logf(rd))
                 + 5.0f * fabsf(dist - 2.04f);
    float netE = 0.5f * energy;

    int4 m0 = *reinterpret_cast<const int4*>(altmask + (size_t)p0 * 4);
    int4 m1 = *reinterpret_cast<const int4*>(altmask + (size_t)p1 * 4);

    int f0 = ((d0.x * NC + d0.y) * NR + d0.z) * N_ALT;
    int f1 = ((d1.x * NC + d1.y) * NR + d1.z) * N_ALT;

    const int* m0p = &m0.x;
    const int* m1p = &m1.x;
#pragma unroll
    for (int a = 0; a < N_ALT; ++a) {
        if (m0p[a] & m1p[a]) {
            atomicAdd(atomE + (size_t)p0 * N_ALT + a, netE);
            atomicAdd(atomE + (size_t)p1 * N_ALT + a, netE);
            atomicAdd(resE + f0 + a, netE);
            atomicAdd(resE + f1 + a, netE);
        }
    }
}

__device__ __forceinline__ bool probe2(const unsigned int* __restrict__ lm,
                                       int a, int b) {
    unsigned m = (lm[a >> 5] >> (a & 31)) & (lm[b >> 5] >> (b & 31));
    return m & 1u;
}

// Process one batch of 8 pairs (4x int4 already in registers).
__device__ __forceinline__ void process8(
    int4 a0, int4 a1, int4 a2, int4 a3, size_t i0,
    const unsigned int* __restrict__ lmask,
    const float* __restrict__ coords,
    const int*   __restrict__ adesc,
    const int*   __restrict__ altmask,
    float* __restrict__ resE,
    float* __restrict__ atomE,
    float* __restrict__ sulfur)
{
    bool s0 = probe2(lmask, a0.x, a0.y);
    bool s1 = probe2(lmask, a0.z, a0.w);
    bool s2 = probe2(lmask, a1.x, a1.y);
    bool s3 = probe2(lmask, a1.z, a1.w);
    bool s4 = probe2(lmask, a2.x, a2.y);
    bool s5 = probe2(lmask, a2.z, a2.w);
    bool s6 = probe2(lmask, a3.x, a3.y);
    bool s7 = probe2(lmask, a3.z, a3.w);

    float4 sv0 = make_float4(s0 ? 1.0f : 0.0f, s1 ? 1.0f : 0.0f,
                             s2 ? 1.0f : 0.0f, s3 ? 1.0f : 0.0f);
    float4 sv1 = make_float4(s4 ? 1.0f : 0.0f, s5 ? 1.0f : 0.0f,
                             s6 ? 1.0f : 0.0f, s7 ? 1.0f : 0.0f);
    float4* sp = reinterpret_cast<float4*>(sulfur + i0);
    sp[0] = sv0;
    sp[1] = sv1;

    if (s0) heavy_pair(a0.x, a0.y, coords, adesc, altmask, resE, atomE);
    if (s1) heavy_pair(a0.z, a0.w, coords, adesc, altmask, resE, atomE);
    if (s2) heavy_pair(a1.x, a1.y, coords, adesc, altmask, resE, atomE);
    if (s3) heavy_pair(a1.z, a1.w, coords, adesc, altmask, resE, atomE);
    if (s4) heavy_pair(a2.x, a2.y, coords, adesc, altmask, resE, atomE);
    if (s5) heavy_pair(a2.z, a2.w, coords, adesc, altmask, resE, atomE);
    if (s6) heavy_pair(a3.x, a3.y, coords, adesc, altmask, resE, atomE);
    if (s7) heavy_pair(a3.z, a3.w, coords, adesc, altmask, resE, atomE);
}

// ---------------------------------------------------------------------------
// Kernel B: broadcast mask into LDS (uint4), sync, THEN software-pipelined
// grid-stride loop: issue iteration k+1's 4x int4 pair loads before
// processing iteration k. Loads live strictly after the barrier (the
// round-7 loads-before-barrier variant forced a block-wide vmcnt(0) drain
// at s_barrier and regressed 29->38 us).
// 1024-thread blocks, 62.5 KB LDS -> 2 blocks/CU = 32 waves/CU.
// ---------------------------------------------------------------------------
__global__ __launch_bounds__(1024) void disulfide_pair_kernel(
    const float* __restrict__ coords,
    const int*   __restrict__ adesc,    // (N,4)
    const int*   __restrict__ pairs,    // (P,2)
    const int*   __restrict__ altmask,  // (N,4) 0/1
    const unsigned int* __restrict__ sgmask32,
    float* __restrict__ resE,
    float* __restrict__ atomE,
    float* __restrict__ sulfur,
    int P)
{
    __shared__ unsigned int lmask[MASK_V4 * 4];   // 62,512 B

    {
        const uint4* g4 = reinterpret_cast<const uint4*>(sgmask32);
        uint4* l4 = reinterpret_cast<uint4*>(lmask);
#pragma unroll
        for (int k = 0; k < 4; ++k) {
            int w = threadIdx.x + k * 1024;
            if (w < MASK_V4) l4[w] = g4[w];
        }
    }
    __syncthreads();

    const size_t tid    = (size_t)blockIdx.x * 1024 + threadIdx.x;
    const size_t stride = (size_t)gridDim.x * 1024 * 8;
    const size_t Pz     = (size_t)P;

    size_t i = tid * 8;
    if (i >= Pz) return;

    // Prologue: load batch for iteration 0.
    const int4* pp = reinterpret_cast<const int4*>(pairs + i * 2);
    int4 a0 = pp[0], a1 = pp[1], a2 = pp[2], a3 = pp[3];

    while (true) {
        // Prefetch next iteration's batch (independent — stays in flight
        // across process8's probes/stores).
        size_t inext = i + stride;
        bool haveb = (inext < Pz);
        int4 b0, b1, b2, b3;
        if (haveb) {
            const int4* pn = reinterpret_cast<const int4*>(pairs + inext * 2);
            b0 = pn[0]; b1 = pn[1]; b2 = pn[2]; b3 = pn[3];
        }

        process8(a0, a1, a2, a3, i, lmask,
                 coords, adesc, altmask, resE, atomE, sulfur);

        if (!haveb) break;
        a0 = b0; a1 = b1; a2 = b2; a3 = b3;
        i = inext;
    }
}

extern "C" void kernel_launch(void* const* d_in, const int* in_sizes, int n_in,
                              void* d_out, int out_size, void* d_ws, size_t ws_size,
                              hipStream_t stream) {
    const float* coords  = (const float*)d_in[0];
    const int*   adesc   = (const int*)d_in[1];
    // d_in[2] = atom_number (unused)
    const int*   pairs   = (const int*)d_in[3];
    const int*   altmask = (const int*)d_in[4];
    // d_in[5] = partners (unused), d_in[6] = facc (unused)

    const int P = in_sizes[3] / 2;   // 8,000,000

    float* out    = (float*)d_out;
    float* resE   = out;
    float* atomE  = out + RESE_SIZE;
    float* sulfur = out + RESE_SIZE + ATOME_SIZE;

    unsigned long long* sgmask = (unsigned long long*)d_ws;   // 62.5 KB

    // Kernel A: zero accumulated outputs + build SG bitmask (one launch).
    {
        const int threads = 1024;
        const int blocks  = (ZERO_F4 + threads - 1) / threads;   // 879
        prep_kernel<<<blocks, threads, 0, stream>>>(adesc, resE, sgmask);
    }

    // Kernel B: pipelined pair streaming with LDS-resident bitmask.
    {
        const int threads = 1024;
        const int blocks  = 512;     // 2 resident blocks/CU on 256 CUs
        disulfide_pair_kernel<<<blocks, threads, 0, stream>>>(
            coords, adesc, pairs, altmask, (const unsigned int*)sgmask,
            resE, atomE, sulfur, P);
    }
}